// Round 17
// baseline (187.490 us; speedup 1.0000x reference)
//
#include <hip/hip_runtime.h>
#include <stdint.h>

typedef unsigned short u16;
typedef __bf16 bf16x4 __attribute__((ext_vector_type(4)));
typedef __bf16 bf16x8 __attribute__((ext_vector_type(8)));
typedef float f32x4 __attribute__((ext_vector_type(4)));

#define EMBED 1024
#define NHEAD 16
#define HDIM  64
#define BATCH 2
#define SEQ   2048
#define MROWS 4096

// f32 -> bf16 round-to-nearest-even (inputs are finite)
__device__ __forceinline__ u16 f2bf(float f) {
  union { float f; uint32_t u; } v; v.f = f;
  uint32_t u = v.u;
  return (u16)((u + 0x7FFFu + ((u >> 16) & 1u)) >> 16);
}

// raw hardware 2^x (TRANS pipe, single inst; denorm flush -> 0 is desired)
__device__ __forceinline__ float exp2_fast(float x) {
  float r; asm("v_exp_f32 %0, %1" : "=v"(r) : "v"(x)); return r;
}

// async global->LDS, 16B per lane. LDS dest must be linear: wave base + lane*16.
__device__ __forceinline__ void gload16(const void* g, void* l) {
  __builtin_amdgcn_global_load_lds(
      (__attribute__((address_space(1))) uint32_t*)g,
      (__attribute__((address_space(3))) uint32_t*)l, 16, 0, 0);
}

// ---------------------------------------------------------------------------
// Kernel 1: convert x, Wq, Wk, Wv, Wo from f32 to bf16 (one fused launch)
// ---------------------------------------------------------------------------
__global__ __launch_bounds__(256) void convert_all(
    const float* __restrict__ x,  const float* __restrict__ wq,
    const float* __restrict__ wk, const float* __restrict__ wv,
    const float* __restrict__ wo,
    u16* __restrict__ xb, u16* __restrict__ wqb, u16* __restrict__ wkb,
    u16* __restrict__ wvb, u16* __restrict__ wob)
{
  int i4 = (blockIdx.x * 256 + threadIdx.x) * 4;
  const float* src; u16* dst; int off;
  if      (i4 < 4194304) { src = x;  dst = xb;  off = i4; }
  else if (i4 < 5242880) { src = wq; dst = wqb; off = i4 - 4194304; }
  else if (i4 < 6291456) { src = wk; dst = wkb; off = i4 - 5242880; }
  else if (i4 < 7340032) { src = wv; dst = wvb; off = i4 - 6291456; }
  else                   { src = wo; dst = wob; off = i4 - 7340032; }
  float4 v = *(const float4*)&src[off];
  ushort4 u;
  u.x = f2bf(v.x); u.y = f2bf(v.y); u.z = f2bf(v.z); u.w = f2bf(v.w);
  *(ushort4*)&dst[off] = u;
}

// ---------------------------------------------------------------------------
// Kernel 2: FUSED QKV projection GEMM — r11 EXACT (measured best: 42.5us,
// FETCH 28.7MB). 128x128 tile, grid 768, 2-phase dbuf, one __syncthreads
// per K-step, my-major XCD chunking (768 = 8 x 96).
// mode = nx>>3:  0: Q*(0.125*log2e) -> [B,H,T,D]  1: K -> [B,H,T,D]
//                2: V -> [B,H,D,T] with t PI-PERMUTED within each 64-tile
// ---------------------------------------------------------------------------
__global__ __launch_bounds__(256) void gemm_qkv(
    const u16* __restrict__ Ab, const u16* __restrict__ Wq,
    const u16* __restrict__ Wk, const u16* __restrict__ Wv,
    u16* __restrict__ Qb, u16* __restrict__ Kb, u16* __restrict__ Vt)
{
  const int bid = blockIdx.x;                     // 0..767
  const int wg = (bid & 7) * 96 + (bid >> 3);     // XCD-chunked, bijective
  const int my = wg / 24, nx = wg % 24;
  const int mode = nx >> 3;
  const u16* Bw = (mode == 0) ? Wq : (mode == 1) ? Wk : Wv;
  const int m0 = my * 128, n0 = (nx & 7) * 128;

  __shared__ __align__(16) u16 As[2][128 * 32];
  __shared__ __align__(16) u16 Bs[2][128 * 32];
  const int tid = threadIdx.x;
  const int lane = tid & 63, wid = tid >> 6;
  const int c = lane & 15, g = lane >> 4;
  const int wm = wid >> 1, wn = wid & 1;

  f32x4 acc[4][4] = {};

  auto stage = [&](int buf, int kt) {
#pragma unroll
    for (int i = 0; i < 2; ++i) {
      int ch = tid + i * 256;               // 0..511 (16B chunks)
      int row = ch >> 2, col8 = (ch & 3) * 8;   // 128 rows x 32 cols
      gload16(Ab + (m0 + row) * 1024 + kt * 32 + col8, &As[buf][ch * 8]);
      gload16(Bw + (n0 + row) * 1024 + kt * 32 + col8, &Bs[buf][ch * 8]);
    }
  };

  stage(0, 0);
  __syncthreads();                          // drains prologue vmcnt

  for (int kt = 0; kt < 32; ++kt) {
    const int cur = kt & 1;
    if (kt < 31) stage(cur ^ 1, kt + 1);    // prefetch overlaps compute
    bf16x8 af[4], bfr[4];
#pragma unroll
    for (int mi = 0; mi < 4; ++mi)
      af[mi] = *(const bf16x8*)&As[cur][(wm * 64 + mi * 16 + c) * 32 + g * 8];
#pragma unroll
    for (int ni = 0; ni < 4; ++ni)
      bfr[ni] = *(const bf16x8*)&Bs[cur][(wn * 64 + ni * 16 + c) * 32 + g * 8];
#pragma unroll
    for (int mi = 0; mi < 4; ++mi)
#pragma unroll
      for (int ni = 0; ni < 4; ++ni)
        acc[mi][ni] = __builtin_amdgcn_mfma_f32_16x16x32_bf16(
            af[mi], bfr[ni], acc[mi][ni], 0, 0, 0);
    __syncthreads();   // one barrier/K-step: prefetch landed + reads done
  }

  // epilogue: C/D layout col = lane&15, row = (lane>>4)*4 + reg  [measured]
  const int gm = m0 + wm * 64;
  const int gn = n0 + wn * 64;
  if (mode < 2) {
    u16* Out = (mode == 0) ? Qb : Kb;
    // 1/sqrt(64) * log2(e) folded into Q
    const float sc = (mode == 0) ? 0.18033688011112042f : 1.0f;
#pragma unroll
    for (int mi = 0; mi < 4; ++mi)
#pragma unroll
      for (int ni = 0; ni < 4; ++ni)
#pragma unroll
        for (int r = 0; r < 4; ++r) {
          int m = gm + mi * 16 + 4 * g + r;
          int n = gn + ni * 16 + c;
          int b = m >> 11, t = m & 2047, h = n >> 6, d = n & 63;
          Out[((b * NHEAD + h) * SEQ + t) * HDIM + d] = f2bf(acc[mi][ni][r] * sc);
        }
  } else {
    // V transposed + pi-permuted: Vt[b,h,d, (t&~63) + pi(t&63)]
#pragma unroll
    for (int mi = 0; mi < 4; ++mi)
#pragma unroll
      for (int ni = 0; ni < 4; ++ni) {
        int m = gm + mi * 16 + 4 * g;       // base t (4 consecutive, 4-aligned)
        int n = gn + ni * 16 + c;
        int b = m >> 11, t = m & 2047, h = n >> 6, d = n & 63;
        int tl = t & 63;
        int tp = (t & ~63) + (tl >> 5) * 32 + ((tl >> 2) & 3) * 8
                 + ((tl >> 4) & 1) * 4;     // pi: 4-group -> 4-group
        ushort4 pk;
        pk.x = f2bf(acc[mi][ni][0]);
        pk.y = f2bf(acc[mi][ni][1]);
        pk.z = f2bf(acc[mi][ni][2]);
        pk.w = f2bf(acc[mi][ni][3]);
        *(ushort4*)&Vt[((b * NHEAD + h) * HDIM + d) * SEQ + tp] = pk;
      }
  }
}

// ---------------------------------------------------------------------------
// Kernel 3: causal flash attention — NO-LDS direct-from-L2 version.
// Per-XCD K/V working set = 4 heads x 512KB = 2MB, L2-resident (r8 FETCH
// =12MB proves it). LDS staging of L2-fit data is pure overhead (guide
// lesson m169: +26% dropping it): it cost 2 barriers + vmcnt drain + 16
// gload_lds per tile and lock-stepped all 4 waves. Here each wave loads
// K/V fragments DIRECTLY global->reg (contiguous b128 per lane; V is
// pi-permuted so PV B-frag is contiguous), no __shared__, no barriers in
// the main loop — 16 waves/CU slide freely; block-mates share tiles via
// L1/L2. Order: K-loads -> QK^T -> V-loads -> softmax -> PV keeps peak
// VGPR ~100 (<=128 for 4 waves/SIMD) and hides V latency under softmax.
// Static balanced dispatch (r8: per-CU sum = 66 units), XCD L2-chunked.
// No-max exact log2-domain softmax, setprio around MFMA.
// ---------------------------------------------------------------------------
__global__ __launch_bounds__(256, 4) void attn(
    const u16* __restrict__ Qb, const u16* __restrict__ Kb,
    const u16* __restrict__ Vt, u16* __restrict__ Ob)
{
  const int bid = blockIdx.x;                 // 0..1023
  const int xcd = bid & 7, d = bid >> 3;      // d: 0..127 within XCD
  const int p = d >> 5, s = d & 31;           // p: 0..3, s ~ CU within XCD
  const int bh = xcd * 4 + p;                 // 4 heads per XCD (L2-resident)
  const int sp = (s + (p >> 1) * 16) & 31;    // shift pairs 2,3 by 16
  const int qt = (p & 1) ? sp : 31 - sp;      // balanced: per-CU sum = 66
  const int b = bh >> 4, h = bh & 15;
  const int q0 = qt * 64;

  const int tid = threadIdx.x, lane = tid & 63, w = tid >> 6;
  const int c = lane & 15, g = lane >> 4;

  const u16* Qg = Qb + bh * SEQ * HDIM;
  const u16* Kg = Kb + bh * SEQ * HDIM;
  const u16* Vg = Vt + bh * HDIM * SEQ;

  // Q fragment (B-operand): rows q0 + w*16 + c, k = kk*32 + g*8 + j
  bf16x8 qf[2];
#pragma unroll
  for (int kk = 0; kk < 2; ++kk)
    qf[kk] = *(const bf16x8*)&Qg[(q0 + w * 16 + c) * HDIM + kk * 32 + g * 8];

  f32x4 o[4] = {};
  float lacc = 0.f;                           // lane-local denominator

  // per-lane constant address parts
  const u16* Kp = Kg + c * HDIM + g * 8;      // + (k0 + kvt*16)*HDIM + kk*32
  const u16* Vp = Vg + c * SEQ + g * 8;       // + ni*16*SEQ + k0 + kk*32

  for (int j = 0; j <= qt; ++j) {
    const int k0 = j * 64;

    // K fragments direct from global (L1/L2-hot): contiguous b128 per lane
    bf16x8 kf[2][4];
#pragma unroll
    for (int kk = 0; kk < 2; ++kk)
#pragma unroll
      for (int kvt = 0; kvt < 4; ++kvt)
        kf[kk][kvt] = *(const bf16x8*)&Kp[(k0 + kvt * 16) * HDIM + kk * 32];

    // S^T[kv][q]: st[kvt][r] = S[q = c][kv = kvt*16 + 4g + r]  (log2 domain)
    f32x4 st[4] = {};
    __builtin_amdgcn_s_setprio(1);
#pragma unroll
    for (int kk = 0; kk < 2; ++kk)
#pragma unroll
      for (int kvt = 0; kvt < 4; ++kvt)
        st[kvt] = __builtin_amdgcn_mfma_f32_16x16x32_bf16(
            kf[kk][kvt], qf[kk], st[kvt], 0, 0, 0);
    __builtin_amdgcn_s_setprio(0);

    // V fragments direct from global (pi-permuted -> contiguous b128);
    // latency hides under mask+softmax below
    bf16x8 vfr[2][4];
#pragma unroll
    for (int kk = 0; kk < 2; ++kk)
#pragma unroll
      for (int ni = 0; ni < 4; ++ni)
        vfr[kk][ni] = *(const bf16x8*)&Vp[ni * 16 * SEQ + k0 + kk * 32];

    // causal mask (diag tile only)
    if (j == qt) {
      const int qrow = q0 + w * 16 + c;
#pragma unroll
      for (int kvt = 0; kvt < 4; ++kvt)
#pragma unroll
        for (int r = 0; r < 4; ++r) {
          int kv = k0 + kvt * 16 + 4 * g + r;
          st[kvt][r] = (kv <= qrow) ? st[kvt][r] : -1e30f;
        }
    }

    // no-max softmax: p = exp2(S); lane-local l; pack straight into A-frags
    // slot j' = (kvt&1)*4 + r  ->  kv = kk*32 + k'(g,j')
    bf16x8 pa[2];
#pragma unroll
    for (int kvt = 0; kvt < 4; ++kvt)
#pragma unroll
      for (int r = 0; r < 4; ++r) {
        float p2 = exp2_fast(st[kvt][r]);
        lacc += p2;
        pa[kvt >> 1][(kvt & 1) * 4 + r] = (__bf16)p2;
      }

    // PV: O[q][d] += P * V
    __builtin_amdgcn_s_setprio(1);
#pragma unroll
    for (int kk = 0; kk < 2; ++kk)
#pragma unroll
      for (int ni = 0; ni < 4; ++ni)
        o[ni] = __builtin_amdgcn_mfma_f32_16x16x32_bf16(
            pa[kk], vfr[kk][ni], o[ni], 0, 0, 0);
    __builtin_amdgcn_s_setprio(0);
  }

  // epilogue: combine l across lane-groups (once), broadcast 1/l to
  // row-layout, write Ob[b*2048+q][h*64+d]
  float rs = lacc;
  rs += __shfl_xor(rs, 16);
  rs += __shfl_xor(rs, 32);
  const float inv = 1.0f / rs;
  float lr[4];
#pragma unroll
  for (int r = 0; r < 4; ++r) lr[r] = __shfl(inv, 4 * g + r);
#pragma unroll
  for (int ni = 0; ni < 4; ++ni)
#pragma unroll
    for (int r = 0; r < 4; ++r) {
      int nc = h * HDIM + ni * 16 + c;
      int mr = b * SEQ + q0 + w * 16 + 4 * g + r;
      Ob[mr * EMBED + nc] = f2bf(o[ni][r] * lr[r]);
    }
}

// ---------------------------------------------------------------------------
// Kernel 4: output projection (r11 proven: 64x128 tiles, grid 512 =
// 2 blocks/CU, 2-phase dbuf). out = Ob[4096,1024] @ Wo^T + bo   (f32 out)
// XCD-chunked swizzle (512 = 8 x 64). (B = 2MB fits L2.)
// ---------------------------------------------------------------------------
__global__ __launch_bounds__(256) void gemm_out(
    const u16* __restrict__ Ab, const u16* __restrict__ Bw,
    const float* __restrict__ bias, float* __restrict__ Out)
{
  const int bid = blockIdx.x;                   // 0..511
  const int wg = (bid & 7) * 64 + (bid >> 3);   // XCD-chunked, bijective
  const int my = wg >> 3, nx = wg & 7;          // my 0..63, nx 0..7
  const int m0 = my * 64, n0 = nx * 128;

  __shared__ __align__(16) u16 As[2][64 * 32];
  __shared__ __align__(16) u16 Bs[2][128 * 32];
  const int tid = threadIdx.x;
  const int lane = tid & 63, wid = tid >> 6;
  const int c = lane & 15, g = lane >> 4;
  const int wm = wid >> 1, wn = wid & 1;        // wave out: 32x64

  f32x4 acc[2][4] = {};

  auto stage = [&](int buf, int kt) {
    {
      int ch = tid;
      int row = ch >> 2, col8 = (ch & 3) * 8;
      gload16(Ab + (m0 + row) * 1024 + kt * 32 + col8, &As[buf][ch * 8]);
    }
#pragma unroll
    for (int i = 0; i < 2; ++i) {
      int ch = tid + i * 256;
      int row = ch >> 2, col8 = (ch & 3) * 8;
      gload16(Bw + (n0 + row) * 1024 + kt * 32 + col8, &Bs[buf][ch * 8]);
    }
  };

  stage(0, 0);
  __syncthreads();

  for (int kt = 0; kt < 32; ++kt) {
    const int cur = kt & 1;
    if (kt < 31) stage(cur ^ 1, kt + 1);
    bf16x8 af[2], bfr[4];
#pragma unroll
    for (int mi = 0; mi < 2; ++mi)
      af[mi] = *(const bf16x8*)&As[cur][(wm * 32 + mi * 16 + c) * 32 + g * 8];
#pragma unroll
    for (int ni = 0; ni < 4; ++ni)
      bfr[ni] = *(const bf16x8*)&Bs[cur][(wn * 64 + ni * 16 + c) * 32 + g * 8];
#pragma unroll
    for (int mi = 0; mi < 2; ++mi)
#pragma unroll
      for (int ni = 0; ni < 4; ++ni)
        acc[mi][ni] = __builtin_amdgcn_mfma_f32_16x16x32_bf16(
            af[mi], bfr[ni], acc[mi][ni], 0, 0, 0);
    __syncthreads();
  }

  const int gm = m0 + wm * 32;
  const int gn = n0 + wn * 64;
#pragma unroll
  for (int mi = 0; mi < 2; ++mi)
#pragma unroll
    for (int ni = 0; ni < 4; ++ni)
#pragma unroll
      for (int r = 0; r < 4; ++r) {
        int m = gm + mi * 16 + 4 * g + r;
        int n = gn + ni * 16 + c;
        Out[m * 1024 + n] = acc[mi][ni][r] + bias[n];
      }
}

// ---------------------------------------------------------------------------
// Workspace layout (bytes):
//   0        xb   [4096,1024] bf16   8388608
//   8388608  Wqb  [1024,1024] bf16   2097152
//  10485760  Wkb                     2097152
//  12582912  Wvb                     2097152
//  14680064  Wob                     2097152
//  16777216  Qb   [B,H,T,D]  bf16    8388608   (pre-scaled by 0.125*log2e)
//  25165824  Kb   [B,H,T,D]  bf16    8388608
//  33554432  Vt   [B,H,D,T] bf16 pi-permuted   8388608
//  41943040  Ob   [4096,1024] bf16   8388608
// ---------------------------------------------------------------------------
extern "C" void kernel_launch(void* const* d_in, const int* in_sizes, int n_in,
                              void* d_out, int out_size, void* d_ws, size_t ws_size,
                              hipStream_t stream) {
  const float* x  = (const float*)d_in[0];
  const float* Wq = (const float*)d_in[1];
  const float* Wk = (const float*)d_in[2];
  const float* Wv = (const float*)d_in[3];
  const float* Wo = (const float*)d_in[4];
  const float* bo = (const float*)d_in[5];
  char* ws = (char*)d_ws;
  u16* xb  = (u16*)(ws);
  u16* wqb = (u16*)(ws + 8388608);
  u16* wkb = (u16*)(ws + 10485760);
  u16* wvb = (u16*)(ws + 12582912);
  u16* wob = (u16*)(ws + 14680064);
  u16* Qb  = (u16*)(ws + 16777216);
  u16* Kb  = (u16*)(ws + 25165824);
  u16* Vt  = (u16*)(ws + 33554432);
  u16* Ob  = (u16*)(ws + 41943040);

  convert_all<<<8192, 256, 0, stream>>>(x, Wq, Wk, Wv, Wo,
                                        xb, wqb, wkb, wvb, wob);
  gemm_qkv<<<dim3(768), 256, 0, stream>>>(xb, wqb, wkb, wvb, Qb, Kb, Vt);
  attn<<<dim3(1024), 256, 0, stream>>>(Qb, Kb, Vt, Ob);
  gemm_out<<<dim3(512), 256, 0, stream>>>(Ob, wob, bo, (float*)d_out);
}

// Round 18
// 110.382 us; speedup vs baseline: 1.6986x; 1.6986x over previous
//
#include <hip/hip_runtime.h>
#include <stdint.h>

typedef unsigned short u16;
typedef __bf16 bf16x4 __attribute__((ext_vector_type(4)));
typedef __bf16 bf16x8 __attribute__((ext_vector_type(8)));
typedef float f32x4 __attribute__((ext_vector_type(4)));

#define EMBED 1024
#define NHEAD 16
#define HDIM  64
#define BATCH 2
#define SEQ   2048
#define MROWS 4096

// f32 -> bf16 round-to-nearest-even (inputs are finite)
__device__ __forceinline__ u16 f2bf(float f) {
  union { float f; uint32_t u; } v; v.f = f;
  uint32_t u = v.u;
  return (u16)((u + 0x7FFFu + ((u >> 16) & 1u)) >> 16);
}

// raw hardware 2^x (TRANS pipe, single inst; denorm flush -> 0 is desired)
__device__ __forceinline__ float exp2_fast(float x) {
  float r; asm("v_exp_f32 %0, %1" : "=v"(r) : "v"(x)); return r;
}

// async global->LDS, 16B per lane. LDS dest must be linear: wave base + lane*16.
__device__ __forceinline__ void gload16(const void* g, void* l) {
  __builtin_amdgcn_global_load_lds(
      (__attribute__((address_space(1))) uint32_t*)g,
      (__attribute__((address_space(3))) uint32_t*)l, 16, 0, 0);
}

// ---------------------------------------------------------------------------
// Kernel 1: convert Wq,Wk,Wv,Wo f32 -> bf16 (x is now consumed as f32
// directly by gemm_qkv — its conversion is fused into the A-fragment load).
// 4 x 1048576 elements, 4 per thread -> grid 4096.
// ---------------------------------------------------------------------------
__global__ __launch_bounds__(256) void convert_w(
    const float* __restrict__ wq, const float* __restrict__ wk,
    const float* __restrict__ wv, const float* __restrict__ wo,
    u16* __restrict__ wqb, u16* __restrict__ wkb,
    u16* __restrict__ wvb, u16* __restrict__ wob)
{
  int i4 = (blockIdx.x * 256 + threadIdx.x) * 4;
  const float* src; u16* dst; int off;
  if      (i4 < 1048576) { src = wq; dst = wqb; off = i4; }
  else if (i4 < 2097152) { src = wk; dst = wkb; off = i4 - 1048576; }
  else if (i4 < 3145728) { src = wv; dst = wvb; off = i4 - 2097152; }
  else                   { src = wo; dst = wob; off = i4 - 3145728; }
  float4 v = *(const float4*)&src[off];
  ushort4 u;
  u.x = f2bf(v.x); u.y = f2bf(v.y); u.z = f2bf(v.z); u.w = f2bf(v.w);
  *(ushort4*)&dst[off] = u;
}

// ---------------------------------------------------------------------------
// Kernel 2: FUSED QKV projection GEMM — r11 structure (128x128, grid 768,
// 2-phase dbuf, one __syncthreads per K-step, my-major XCD chunking) with
// x-CONVERSION FUSED: A is staged as f32 straight from the input tensor
// (LDS As = f32, XOR-swizzled c8^(row&7) to kill the 128B-stride 16-way
// bank conflict; source-side pre-swizzle, linear dest — rule #21), and
// converted to bf16 at fragment-load (2 ds_read_b128 + 8 casts, fits the
// ~64% idle VALU). Saves the separate x convert pass (~6us of the 9us
// convert kernel). LDS 48KB -> still 3 blocks/CU.
// mode = nx>>3:  0: Q*(0.125*log2e) -> [B,H,T,D]  1: K -> [B,H,T,D]
//                2: V -> [B,H,D,T] with t PI-PERMUTED within each 64-tile
// ---------------------------------------------------------------------------
__global__ __launch_bounds__(256) void gemm_qkv(
    const float* __restrict__ Ax, const u16* __restrict__ Wq,
    const u16* __restrict__ Wk, const u16* __restrict__ Wv,
    u16* __restrict__ Qb, u16* __restrict__ Kb, u16* __restrict__ Vt)
{
  const int bid = blockIdx.x;                     // 0..767
  const int wg = (bid & 7) * 96 + (bid >> 3);     // XCD-chunked, bijective
  const int my = wg / 24, nx = wg % 24;
  const int mode = nx >> 3;
  const u16* Bw = (mode == 0) ? Wq : (mode == 1) ? Wk : Wv;
  const int m0 = my * 128, n0 = (nx & 7) * 128;

  __shared__ __align__(16) float As[2][128 * 32];   // f32 A, swizzled chunks
  __shared__ __align__(16) u16  Bs[2][128 * 32];
  const int tid = threadIdx.x;
  const int lane = tid & 63, wid = tid >> 6;
  const int c = lane & 15, g = lane >> 4;
  const int wm = wid >> 1, wn = wid & 1;

  f32x4 acc[4][4] = {};

  auto stage = [&](int buf, int kt) {
    // A: 128 rows x 32 f32 = 1024 16B-chunks (4/thread), 8 chunks/row,
    // source chunk pre-swizzled: LDS[row][c8] = G[row][c8 ^ (row&7)]
#pragma unroll
    for (int i = 0; i < 4; ++i) {
      int ch = tid + i * 256;
      int row = ch >> 3, c8 = ch & 7;
      int sc8 = c8 ^ (row & 7);
      gload16(Ax + (m0 + row) * 1024 + kt * 32 + sc8 * 4, &As[buf][ch * 4]);
    }
    // B: 128 rows x 32 bf16 = 512 chunks (2/thread), linear (b128 reads of
    // B are conflict-light: lanes c stride 64B -> 2-way, free per m136)
#pragma unroll
    for (int i = 0; i < 2; ++i) {
      int ch = tid + i * 256;
      int row = ch >> 2, col8 = (ch & 3) * 8;
      gload16(Bw + (n0 + row) * 1024 + kt * 32 + col8, &Bs[buf][ch * 8]);
    }
  };

  stage(0, 0);
  __syncthreads();                          // drains prologue vmcnt

  for (int kt = 0; kt < 32; ++kt) {
    const int cur = kt & 1;
    if (kt < 31) stage(cur ^ 1, kt + 1);    // prefetch overlaps compute
    bf16x8 af[4], bfr[4];
#pragma unroll
    for (int mi = 0; mi < 4; ++mi) {
      const int row = wm * 64 + mi * 16 + c;
      // k = g*8 + j -> float chunks 2g (j 0..3), 2g+1 (j 4..7), swizzled
      f32x4 lo = *(const f32x4*)&As[cur][row * 32 + (((2 * g) ^ (row & 7)) * 4)];
      f32x4 hi = *(const f32x4*)&As[cur][row * 32 + (((2 * g + 1) ^ (row & 7)) * 4)];
      bf16x8 a;
      a[0] = (__bf16)lo[0]; a[1] = (__bf16)lo[1];
      a[2] = (__bf16)lo[2]; a[3] = (__bf16)lo[3];
      a[4] = (__bf16)hi[0]; a[5] = (__bf16)hi[1];
      a[6] = (__bf16)hi[2]; a[7] = (__bf16)hi[3];
      af[mi] = a;
    }
#pragma unroll
    for (int ni = 0; ni < 4; ++ni)
      bfr[ni] = *(const bf16x8*)&Bs[cur][(wn * 64 + ni * 16 + c) * 32 + g * 8];
#pragma unroll
    for (int mi = 0; mi < 4; ++mi)
#pragma unroll
      for (int ni = 0; ni < 4; ++ni)
        acc[mi][ni] = __builtin_amdgcn_mfma_f32_16x16x32_bf16(
            af[mi], bfr[ni], acc[mi][ni], 0, 0, 0);
    __syncthreads();   // one barrier/K-step: prefetch landed + reads done
  }

  // epilogue: C/D layout col = lane&15, row = (lane>>4)*4 + reg  [measured]
  const int gm = m0 + wm * 64;
  const int gn = n0 + wn * 64;
  if (mode < 2) {
    u16* Out = (mode == 0) ? Qb : Kb;
    // 1/sqrt(64) * log2(e) folded into Q
    const float sc = (mode == 0) ? 0.18033688011112042f : 1.0f;
#pragma unroll
    for (int mi = 0; mi < 4; ++mi)
#pragma unroll
      for (int ni = 0; ni < 4; ++ni)
#pragma unroll
        for (int r = 0; r < 4; ++r) {
          int m = gm + mi * 16 + 4 * g + r;
          int n = gn + ni * 16 + c;
          int b = m >> 11, t = m & 2047, h = n >> 6, d = n & 63;
          Out[((b * NHEAD + h) * SEQ + t) * HDIM + d] = f2bf(acc[mi][ni][r] * sc);
        }
  } else {
    // V transposed + pi-permuted: Vt[b,h,d, (t&~63) + pi(t&63)]
#pragma unroll
    for (int mi = 0; mi < 4; ++mi)
#pragma unroll
      for (int ni = 0; ni < 4; ++ni) {
        int m = gm + mi * 16 + 4 * g;       // base t (4 consecutive, 4-aligned)
        int n = gn + ni * 16 + c;
        int b = m >> 11, t = m & 2047, h = n >> 6, d = n & 63;
        int tl = t & 63;
        int tp = (t & ~63) + (tl >> 5) * 32 + ((tl >> 2) & 3) * 8
                 + ((tl >> 4) & 1) * 4;     // pi: 4-group -> 4-group
        ushort4 pk;
        pk.x = f2bf(acc[mi][ni][0]);
        pk.y = f2bf(acc[mi][ni][1]);
        pk.z = f2bf(acc[mi][ni][2]);
        pk.w = f2bf(acc[mi][ni][3]);
        *(ushort4*)&Vt[((b * NHEAD + h) * HDIM + d) * SEQ + tp] = pk;
      }
  }
}

// ---------------------------------------------------------------------------
// Kernel 3: causal flash attention — r8 EXACT (best measured: ~38us).
// r17 proved the LDS+gload_lds prefetch pipeline is essential: the no-LDS
// direct-from-L2 variant was 3.3x slower (latency serialization, MfmaUtil
// 5.5%). Single q-tile/block, balanced per-CU dispatch (sum = 66 units),
// XCD L2-chunked, dbuf, XOR-swizzled LDS, swapped QK^T, no-max exact
// log2-domain softmax, pi-permuted V, setprio.
// ---------------------------------------------------------------------------
__global__ __launch_bounds__(256, 4) void attn(
    const u16* __restrict__ Qb, const u16* __restrict__ Kb,
    const u16* __restrict__ Vt, u16* __restrict__ Ob)
{
  const int bid = blockIdx.x;                 // 0..1023
  const int xcd = bid & 7, d = bid >> 3;      // d: 0..127 within XCD
  const int p = d >> 5, s = d & 31;           // p: 0..3, s ~ CU within XCD
  const int bh = xcd * 4 + p;                 // 4 heads per XCD (L2-resident)
  const int sp = (s + (p >> 1) * 16) & 31;    // shift pairs 2,3 by 16
  const int qt = (p & 1) ? sp : 31 - sp;      // balanced: per-CU sum = 66
  const int b = bh >> 4, h = bh & 15;
  const int q0 = qt * 64;

  __shared__ __align__(16) u16 Ks[2][64 * 64];
  __shared__ __align__(16) u16 Vs[2][64 * 64];      // Vs[d][pi(t_local)]

  const int tid = threadIdx.x, lane = tid & 63, w = tid >> 6;
  const int c = lane & 15, g = lane >> 4;

  const u16* Qg = Qb + bh * SEQ * HDIM;
  const u16* Kg = Kb + bh * SEQ * HDIM;
  const u16* Vg = Vt + bh * HDIM * SEQ;

  // Q fragment (B-operand): rows q0 + w*16 + c, k = kk*32 + g*8 + j
  bf16x8 qf[2];
#pragma unroll
  for (int kk = 0; kk < 2; ++kk)
    qf[kk] = *(const bf16x8*)&Qg[(q0 + w * 16 + c) * HDIM + kk * 32 + g * 8];

  f32x4 o[4] = {};
  float lacc = 0.f;                           // lane-local denominator

  auto stage = [&](int buf, int j) {
    const int k0 = j * 64;
#pragma unroll
    for (int i = 0; i < 2; ++i) {
      int ch = tid + i * 256;                 // 0..511
      int row = ch >> 3, c8 = ch & 7;         // 64 rows x 8 chunks
      int sc8 = c8 ^ (row & 7);               // pre-swizzled source chunk
      gload16(Kg + (k0 + row) * HDIM + sc8 * 8, &Ks[buf][ch * 8]);
      gload16(Vg + row * SEQ + k0 + sc8 * 8, &Vs[buf][ch * 8]);
    }
  };

  stage(0, 0);
  __syncthreads();

  for (int j = 0; j <= qt; ++j) {
    const int cur = j & 1;
    if (j < qt) stage(cur ^ 1, j + 1);        // prefetch overlaps compute
    const int k0 = j * 64;

    // S^T[kv][q]: st[kvt][r] = S[q = c][kv = kvt*16 + 4g + r]  (log2 domain)
    f32x4 st[4] = {};
    __builtin_amdgcn_s_setprio(1);
#pragma unroll
    for (int kk = 0; kk < 2; ++kk)
#pragma unroll
      for (int kvt = 0; kvt < 4; ++kvt) {
        const int R = kvt * 16 + c;
        bf16x8 kf = *(const bf16x8*)
            &Ks[cur][R * 64 + (((kk * 4 + g) ^ (R & 7)) * 8)];
        st[kvt] = __builtin_amdgcn_mfma_f32_16x16x32_bf16(kf, qf[kk], st[kvt], 0, 0, 0);
      }
    __builtin_amdgcn_s_setprio(0);

    // causal mask (diag tile only)
    if (j == qt) {
      const int qrow = q0 + w * 16 + c;
#pragma unroll
      for (int kvt = 0; kvt < 4; ++kvt)
#pragma unroll
        for (int r = 0; r < 4; ++r) {
          int kv = k0 + kvt * 16 + 4 * g + r;
          st[kvt][r] = (kv <= qrow) ? st[kvt][r] : -1e30f;
        }
    }

    // no-max softmax: p = exp2(S); lane-local l; pack straight into A-frags
    // slot j' = (kvt&1)*4 + r  ->  kv = kk*32 + k'(g,j')
    bf16x8 pa[2];
#pragma unroll
    for (int kvt = 0; kvt < 4; ++kvt)
#pragma unroll
      for (int r = 0; r < 4; ++r) {
        float p2 = exp2_fast(st[kvt][r]);
        lacc += p2;
        pa[kvt >> 1][(kvt & 1) * 4 + r] = (__bf16)p2;
      }

    // PV: O[q][d] += P * V; pi-permuted V -> one b128, same form as K read
    __builtin_amdgcn_s_setprio(1);
#pragma unroll
    for (int kk = 0; kk < 2; ++kk)
#pragma unroll
      for (int ni = 0; ni < 4; ++ni) {
        const int dd = ni * 16 + c;
        bf16x8 vf = *(const bf16x8*)
            &Vs[cur][dd * 64 + (((kk * 4 + g) ^ (dd & 7)) * 8)];
        o[ni] = __builtin_amdgcn_mfma_f32_16x16x32_bf16(pa[kk], vf, o[ni], 0, 0, 0);
      }
    __builtin_amdgcn_s_setprio(0);

    __syncthreads();           // LDS reads done + prefetch drained
  }

  // epilogue: combine l across lane-groups (once), broadcast 1/l to
  // row-layout, write Ob[b*2048+q][h*64+d]
  float rs = lacc;
  rs += __shfl_xor(rs, 16);
  rs += __shfl_xor(rs, 32);
  const float inv = 1.0f / rs;
  float lr[4];
#pragma unroll
  for (int r = 0; r < 4; ++r) lr[r] = __shfl(inv, 4 * g + r);
#pragma unroll
  for (int ni = 0; ni < 4; ++ni)
#pragma unroll
    for (int r = 0; r < 4; ++r) {
      int nc = h * HDIM + ni * 16 + c;
      int mr = b * SEQ + q0 + w * 16 + 4 * g + r;
      Ob[mr * EMBED + nc] = f2bf(o[ni][r] * lr[r]);
    }
}

// ---------------------------------------------------------------------------
// Kernel 4: output projection (r11 proven: 64x128 tiles, grid 512 =
// 2 blocks/CU, 2-phase dbuf). out = Ob[4096,1024] @ Wo^T + bo   (f32 out)
// XCD-chunked swizzle (512 = 8 x 64). (B = 2MB fits L2.)
// ---------------------------------------------------------------------------
__global__ __launch_bounds__(256) void gemm_out(
    const u16* __restrict__ Ab, const u16* __restrict__ Bw,
    const float* __restrict__ bias, float* __restrict__ Out)
{
  const int bid = blockIdx.x;                   // 0..511
  const int wg = (bid & 7) * 64 + (bid >> 3);   // XCD-chunked, bijective
  const int my = wg >> 3, nx = wg & 7;          // my 0..63, nx 0..7
  const int m0 = my * 64, n0 = nx * 128;

  __shared__ __align__(16) u16 As[2][64 * 32];
  __shared__ __align__(16) u16 Bs[2][128 * 32];
  const int tid = threadIdx.x;
  const int lane = tid & 63, wid = tid >> 6;
  const int c = lane & 15, g = lane >> 4;
  const int wm = wid >> 1, wn = wid & 1;        // wave out: 32x64

  f32x4 acc[2][4] = {};

  auto stage = [&](int buf, int kt) {
    {
      int ch = tid;
      int row = ch >> 2, col8 = (ch & 3) * 8;
      gload16(Ab + (m0 + row) * 1024 + kt * 32 + col8, &As[buf][ch * 8]);
    }
#pragma unroll
    for (int i = 0; i < 2; ++i) {
      int ch = tid + i * 256;
      int row = ch >> 2, col8 = (ch & 3) * 8;
      gload16(Bw + (n0 + row) * 1024 + kt * 32 + col8, &Bs[buf][ch * 8]);
    }
  };

  stage(0, 0);
  __syncthreads();

  for (int kt = 0; kt < 32; ++kt) {
    const int cur = kt & 1;
    if (kt < 31) stage(cur ^ 1, kt + 1);
    bf16x8 af[2], bfr[4];
#pragma unroll
    for (int mi = 0; mi < 2; ++mi)
      af[mi] = *(const bf16x8*)&As[cur][(wm * 32 + mi * 16 + c) * 32 + g * 8];
#pragma unroll
    for (int ni = 0; ni < 4; ++ni)
      bfr[ni] = *(const bf16x8*)&Bs[cur][(wn * 64 + ni * 16 + c) * 32 + g * 8];
#pragma unroll
    for (int mi = 0; mi < 2; ++mi)
#pragma unroll
      for (int ni = 0; ni < 4; ++ni)
        acc[mi][ni] = __builtin_amdgcn_mfma_f32_16x16x32_bf16(
            af[mi], bfr[ni], acc[mi][ni], 0, 0, 0);
    __syncthreads();
  }

  const int gm = m0 + wm * 32;
  const int gn = n0 + wn * 64;
#pragma unroll
  for (int mi = 0; mi < 2; ++mi)
#pragma unroll
    for (int ni = 0; ni < 4; ++ni)
#pragma unroll
      for (int r = 0; r < 4; ++r) {
        int m = gm + mi * 16 + 4 * g + r;
        int n = gn + ni * 16 + c;
        Out[m * 1024 + n] = acc[mi][ni][r] + bias[n];
      }
}

// ---------------------------------------------------------------------------
// Workspace layout (bytes):
//   0        (free — xb no longer used)    8388608
//   8388608  Wqb  [1024,1024] bf16   2097152
//  10485760  Wkb                     2097152
//  12582912  Wvb                     2097152
//  14680064  Wob                     2097152
//  16777216  Qb   [B,H,T,D]  bf16    8388608   (pre-scaled by 0.125*log2e)
//  25165824  Kb   [B,H,T,D]  bf16    8388608
//  33554432  Vt   [B,H,D,T] bf16 pi-permuted   8388608
//  41943040  Ob   [4096,1024] bf16   8388608
// ---------------------------------------------------------------------------
extern "C" void kernel_launch(void* const* d_in, const int* in_sizes, int n_in,
                              void* d_out, int out_size, void* d_ws, size_t ws_size,
                              hipStream_t stream) {
  const float* x  = (const float*)d_in[0];
  const float* Wq = (const float*)d_in[1];
  const float* Wk = (const float*)d_in[2];
  const float* Wv = (const float*)d_in[3];
  const float* Wo = (const float*)d_in[4];
  const float* bo = (const float*)d_in[5];
  char* ws = (char*)d_ws;
  u16* wqb = (u16*)(ws + 8388608);
  u16* wkb = (u16*)(ws + 10485760);
  u16* wvb = (u16*)(ws + 12582912);
  u16* wob = (u16*)(ws + 14680064);
  u16* Qb  = (u16*)(ws + 16777216);
  u16* Kb  = (u16*)(ws + 25165824);
  u16* Vt  = (u16*)(ws + 33554432);
  u16* Ob  = (u16*)(ws + 41943040);

  convert_w<<<4096, 256, 0, stream>>>(Wq, Wk, Wv, Wo, wqb, wkb, wvb, wob);
  gemm_qkv<<<dim3(768), 256, 0, stream>>>(x, wqb, wkb, wvb, Qb, Kb, Vt);
  attn<<<dim3(1024), 256, 0, stream>>>(Qb, Kb, Vt, Ob);
  gemm_out<<<dim3(512), 256, 0, stream>>>(Ob, wob, bo, (float*)d_out);
}

// Round 19
// 104.262 us; speedup vs baseline: 1.7983x; 1.0587x over previous
//
#include <hip/hip_runtime.h>
#include <stdint.h>

typedef unsigned short u16;
typedef __bf16 bf16x4 __attribute__((ext_vector_type(4)));
typedef __bf16 bf16x8 __attribute__((ext_vector_type(8)));
typedef float f32x4 __attribute__((ext_vector_type(4)));

#define EMBED 1024
#define NHEAD 16
#define HDIM  64
#define BATCH 2
#define SEQ   2048
#define MROWS 4096

// f32 -> bf16 round-to-nearest-even (inputs are finite)
__device__ __forceinline__ u16 f2bf(float f) {
  union { float f; uint32_t u; } v; v.f = f;
  uint32_t u = v.u;
  return (u16)((u + 0x7FFFu + ((u >> 16) & 1u)) >> 16);
}

// raw hardware 2^x (TRANS pipe, single inst; denorm flush -> 0 is desired)
__device__ __forceinline__ float exp2_fast(float x) {
  float r; asm("v_exp_f32 %0, %1" : "=v"(r) : "v"(x)); return r;
}

// async global->LDS, 16B per lane. LDS dest must be linear: wave base + lane*16.
__device__ __forceinline__ void gload16(const void* g, void* l) {
  __builtin_amdgcn_global_load_lds(
      (__attribute__((address_space(1))) uint32_t*)g,
      (__attribute__((address_space(3))) uint32_t*)l, 16, 0, 0);
}

// ---------------------------------------------------------------------------
// Kernel 1: convert x, Wq, Wk, Wv, Wo from f32 to bf16 (one fused launch).
// (r18 proved fusing x's conversion into gemm_qkv costs 3x what it saves:
// anything added between the GEMM's two barriers is on the critical path.)
// ---------------------------------------------------------------------------
__global__ __launch_bounds__(256) void convert_all(
    const float* __restrict__ x,  const float* __restrict__ wq,
    const float* __restrict__ wk, const float* __restrict__ wv,
    const float* __restrict__ wo,
    u16* __restrict__ xb, u16* __restrict__ wqb, u16* __restrict__ wkb,
    u16* __restrict__ wvb, u16* __restrict__ wob)
{
  int i4 = (blockIdx.x * 256 + threadIdx.x) * 4;
  const float* src; u16* dst; int off;
  if      (i4 < 4194304) { src = x;  dst = xb;  off = i4; }
  else if (i4 < 5242880) { src = wq; dst = wqb; off = i4 - 4194304; }
  else if (i4 < 6291456) { src = wk; dst = wkb; off = i4 - 5242880; }
  else if (i4 < 7340032) { src = wv; dst = wvb; off = i4 - 6291456; }
  else                   { src = wo; dst = wob; off = i4 - 7340032; }
  float4 v = *(const float4*)&src[off];
  ushort4 u;
  u.x = f2bf(v.x); u.y = f2bf(v.y); u.z = f2bf(v.z); u.w = f2bf(v.w);
  *(ushort4*)&dst[off] = u;
}

// ---------------------------------------------------------------------------
// Kernel 2: FUSED QKV projection GEMM — r11 EXACT (measured best: 42.5us,
// FETCH 28.7MB, MfmaUtil 22.6%). 128x128 tile, grid 768, 2-phase dbuf,
// one __syncthreads per K-step, my-major XCD chunking (768 = 8 x 96).
// Probes r9/r12/r14/r15/r18 established this as the local optimum.
// mode = nx>>3:  0: Q*(0.125*log2e) -> [B,H,T,D]  1: K -> [B,H,T,D]
//                2: V -> [B,H,D,T] with t PI-PERMUTED within each 64-tile
// ---------------------------------------------------------------------------
__global__ __launch_bounds__(256) void gemm_qkv(
    const u16* __restrict__ Ab, const u16* __restrict__ Wq,
    const u16* __restrict__ Wk, const u16* __restrict__ Wv,
    u16* __restrict__ Qb, u16* __restrict__ Kb, u16* __restrict__ Vt)
{
  const int bid = blockIdx.x;                     // 0..767
  const int wg = (bid & 7) * 96 + (bid >> 3);     // XCD-chunked, bijective
  const int my = wg / 24, nx = wg % 24;
  const int mode = nx >> 3;
  const u16* Bw = (mode == 0) ? Wq : (mode == 1) ? Wk : Wv;
  const int m0 = my * 128, n0 = (nx & 7) * 128;

  __shared__ __align__(16) u16 As[2][128 * 32];
  __shared__ __align__(16) u16 Bs[2][128 * 32];
  const int tid = threadIdx.x;
  const int lane = tid & 63, wid = tid >> 6;
  const int c = lane & 15, g = lane >> 4;
  const int wm = wid >> 1, wn = wid & 1;

  f32x4 acc[4][4] = {};

  auto stage = [&](int buf, int kt) {
#pragma unroll
    for (int i = 0; i < 2; ++i) {
      int ch = tid + i * 256;               // 0..511 (16B chunks)
      int row = ch >> 2, col8 = (ch & 3) * 8;   // 128 rows x 32 cols
      gload16(Ab + (m0 + row) * 1024 + kt * 32 + col8, &As[buf][ch * 8]);
      gload16(Bw + (n0 + row) * 1024 + kt * 32 + col8, &Bs[buf][ch * 8]);
    }
  };

  stage(0, 0);
  __syncthreads();                          // drains prologue vmcnt

  for (int kt = 0; kt < 32; ++kt) {
    const int cur = kt & 1;
    if (kt < 31) stage(cur ^ 1, kt + 1);    // prefetch overlaps compute
    bf16x8 af[4], bfr[4];
#pragma unroll
    for (int mi = 0; mi < 4; ++mi)
      af[mi] = *(const bf16x8*)&As[cur][(wm * 64 + mi * 16 + c) * 32 + g * 8];
#pragma unroll
    for (int ni = 0; ni < 4; ++ni)
      bfr[ni] = *(const bf16x8*)&Bs[cur][(wn * 64 + ni * 16 + c) * 32 + g * 8];
#pragma unroll
    for (int mi = 0; mi < 4; ++mi)
#pragma unroll
      for (int ni = 0; ni < 4; ++ni)
        acc[mi][ni] = __builtin_amdgcn_mfma_f32_16x16x32_bf16(
            af[mi], bfr[ni], acc[mi][ni], 0, 0, 0);
    __syncthreads();   // one barrier/K-step: prefetch landed + reads done
  }

  // epilogue: C/D layout col = lane&15, row = (lane>>4)*4 + reg  [measured]
  const int gm = m0 + wm * 64;
  const int gn = n0 + wn * 64;
  if (mode < 2) {
    u16* Out = (mode == 0) ? Qb : Kb;
    // 1/sqrt(64) * log2(e) folded into Q
    const float sc = (mode == 0) ? 0.18033688011112042f : 1.0f;
#pragma unroll
    for (int mi = 0; mi < 4; ++mi)
#pragma unroll
      for (int ni = 0; ni < 4; ++ni)
#pragma unroll
        for (int r = 0; r < 4; ++r) {
          int m = gm + mi * 16 + 4 * g + r;
          int n = gn + ni * 16 + c;
          int b = m >> 11, t = m & 2047, h = n >> 6, d = n & 63;
          Out[((b * NHEAD + h) * SEQ + t) * HDIM + d] = f2bf(acc[mi][ni][r] * sc);
        }
  } else {
    // V transposed + pi-permuted: Vt[b,h,d, (t&~63) + pi(t&63)]
#pragma unroll
    for (int mi = 0; mi < 4; ++mi)
#pragma unroll
      for (int ni = 0; ni < 4; ++ni) {
        int m = gm + mi * 16 + 4 * g;       // base t (4 consecutive, 4-aligned)
        int n = gn + ni * 16 + c;
        int b = m >> 11, t = m & 2047, h = n >> 6, d = n & 63;
        int tl = t & 63;
        int tp = (t & ~63) + (tl >> 5) * 32 + ((tl >> 2) & 3) * 8
                 + ((tl >> 4) & 1) * 4;     // pi: 4-group -> 4-group
        ushort4 pk;
        pk.x = f2bf(acc[mi][ni][0]);
        pk.y = f2bf(acc[mi][ni][1]);
        pk.z = f2bf(acc[mi][ni][2]);
        pk.w = f2bf(acc[mi][ni][3]);
        *(ushort4*)&Vt[((b * NHEAD + h) * HDIM + d) * SEQ + tp] = pk;
      }
  }
}

// ---------------------------------------------------------------------------
// Kernel 3: causal flash attention — r8 EXACT (best measured: ~38us).
// r17 proved the LDS+gload_lds prefetch pipeline is essential (no-LDS
// variant 3.3x slower); r10/r13/r16 proved restructures neutral-negative.
// Single q-tile/block, balanced per-CU dispatch (sum = 66 units), XCD
// L2-chunked, dbuf, XOR-swizzled LDS, swapped QK^T, no-max exact
// log2-domain softmax, pi-permuted V, setprio.
// ---------------------------------------------------------------------------
__global__ __launch_bounds__(256, 4) void attn(
    const u16* __restrict__ Qb, const u16* __restrict__ Kb,
    const u16* __restrict__ Vt, u16* __restrict__ Ob)
{
  const int bid = blockIdx.x;                 // 0..1023
  const int xcd = bid & 7, d = bid >> 3;      // d: 0..127 within XCD
  const int p = d >> 5, s = d & 31;           // p: 0..3, s ~ CU within XCD
  const int bh = xcd * 4 + p;                 // 4 heads per XCD (L2-resident)
  const int sp = (s + (p >> 1) * 16) & 31;    // shift pairs 2,3 by 16
  const int qt = (p & 1) ? sp : 31 - sp;      // balanced: per-CU sum = 66
  const int b = bh >> 4, h = bh & 15;
  const int q0 = qt * 64;

  __shared__ __align__(16) u16 Ks[2][64 * 64];
  __shared__ __align__(16) u16 Vs[2][64 * 64];      // Vs[d][pi(t_local)]

  const int tid = threadIdx.x, lane = tid & 63, w = tid >> 6;
  const int c = lane & 15, g = lane >> 4;

  const u16* Qg = Qb + bh * SEQ * HDIM;
  const u16* Kg = Kb + bh * SEQ * HDIM;
  const u16* Vg = Vt + bh * HDIM * SEQ;

  // Q fragment (B-operand): rows q0 + w*16 + c, k = kk*32 + g*8 + j
  bf16x8 qf[2];
#pragma unroll
  for (int kk = 0; kk < 2; ++kk)
    qf[kk] = *(const bf16x8*)&Qg[(q0 + w * 16 + c) * HDIM + kk * 32 + g * 8];

  f32x4 o[4] = {};
  float lacc = 0.f;                           // lane-local denominator

  auto stage = [&](int buf, int j) {
    const int k0 = j * 64;
#pragma unroll
    for (int i = 0; i < 2; ++i) {
      int ch = tid + i * 256;                 // 0..511
      int row = ch >> 3, c8 = ch & 7;         // 64 rows x 8 chunks
      int sc8 = c8 ^ (row & 7);               // pre-swizzled source chunk
      gload16(Kg + (k0 + row) * HDIM + sc8 * 8, &Ks[buf][ch * 8]);
      gload16(Vg + row * SEQ + k0 + sc8 * 8, &Vs[buf][ch * 8]);
    }
  };

  stage(0, 0);
  __syncthreads();

  for (int j = 0; j <= qt; ++j) {
    const int cur = j & 1;
    if (j < qt) stage(cur ^ 1, j + 1);        // prefetch overlaps compute
    const int k0 = j * 64;

    // S^T[kv][q]: st[kvt][r] = S[q = c][kv = kvt*16 + 4g + r]  (log2 domain)
    f32x4 st[4] = {};
    __builtin_amdgcn_s_setprio(1);
#pragma unroll
    for (int kk = 0; kk < 2; ++kk)
#pragma unroll
      for (int kvt = 0; kvt < 4; ++kvt) {
        const int R = kvt * 16 + c;
        bf16x8 kf = *(const bf16x8*)
            &Ks[cur][R * 64 + (((kk * 4 + g) ^ (R & 7)) * 8)];
        st[kvt] = __builtin_amdgcn_mfma_f32_16x16x32_bf16(kf, qf[kk], st[kvt], 0, 0, 0);
      }
    __builtin_amdgcn_s_setprio(0);

    // causal mask (diag tile only)
    if (j == qt) {
      const int qrow = q0 + w * 16 + c;
#pragma unroll
      for (int kvt = 0; kvt < 4; ++kvt)
#pragma unroll
        for (int r = 0; r < 4; ++r) {
          int kv = k0 + kvt * 16 + 4 * g + r;
          st[kvt][r] = (kv <= qrow) ? st[kvt][r] : -1e30f;
        }
    }

    // no-max softmax: p = exp2(S); lane-local l; pack straight into A-frags
    // slot j' = (kvt&1)*4 + r  ->  kv = kk*32 + k'(g,j')
    bf16x8 pa[2];
#pragma unroll
    for (int kvt = 0; kvt < 4; ++kvt)
#pragma unroll
      for (int r = 0; r < 4; ++r) {
        float p2 = exp2_fast(st[kvt][r]);
        lacc += p2;
        pa[kvt >> 1][(kvt & 1) * 4 + r] = (__bf16)p2;
      }

    // PV: O[q][d] += P * V; pi-permuted V -> one b128, same form as K read
    __builtin_amdgcn_s_setprio(1);
#pragma unroll
    for (int kk = 0; kk < 2; ++kk)
#pragma unroll
      for (int ni = 0; ni < 4; ++ni) {
        const int dd = ni * 16 + c;
        bf16x8 vf = *(const bf16x8*)
            &Vs[cur][dd * 64 + (((kk * 4 + g) ^ (dd & 7)) * 8)];
        o[ni] = __builtin_amdgcn_mfma_f32_16x16x32_bf16(pa[kk], vf, o[ni], 0, 0, 0);
      }
    __builtin_amdgcn_s_setprio(0);

    __syncthreads();           // LDS reads done + prefetch drained
  }

  // epilogue: combine l across lane-groups (once), broadcast 1/l to
  // row-layout, write Ob[b*2048+q][h*64+d]
  float rs = lacc;
  rs += __shfl_xor(rs, 16);
  rs += __shfl_xor(rs, 32);
  const float inv = 1.0f / rs;
  float lr[4];
#pragma unroll
  for (int r = 0; r < 4; ++r) lr[r] = __shfl(inv, 4 * g + r);
#pragma unroll
  for (int ni = 0; ni < 4; ++ni)
#pragma unroll
    for (int r = 0; r < 4; ++r) {
      int nc = h * HDIM + ni * 16 + c;
      int mr = b * SEQ + q0 + w * 16 + 4 * g + r;
      Ob[mr * EMBED + nc] = f2bf(o[ni][r] * lr[r]);
    }
}

// ---------------------------------------------------------------------------
// Kernel 4: output projection (r11 proven: 64x128 tiles, grid 512 =
// 2 blocks/CU, 2-phase dbuf). out = Ob[4096,1024] @ Wo^T + bo   (f32 out)
// XCD-chunked swizzle (512 = 8 x 64). (B = 2MB fits L2.)
// ---------------------------------------------------------------------------
__global__ __launch_bounds__(256) void gemm_out(
    const u16* __restrict__ Ab, const u16* __restrict__ Bw,
    const float* __restrict__ bias, float* __restrict__ Out)
{
  const int bid = blockIdx.x;                   // 0..511
  const int wg = (bid & 7) * 64 + (bid >> 3);   // XCD-chunked, bijective
  const int my = wg >> 3, nx = wg & 7;          // my 0..63, nx 0..7
  const int m0 = my * 64, n0 = nx * 128;

  __shared__ __align__(16) u16 As[2][64 * 32];
  __shared__ __align__(16) u16 Bs[2][128 * 32];
  const int tid = threadIdx.x;
  const int lane = tid & 63, wid = tid >> 6;
  const int c = lane & 15, g = lane >> 4;
  const int wm = wid >> 1, wn = wid & 1;        // wave out: 32x64

  f32x4 acc[2][4] = {};

  auto stage = [&](int buf, int kt) {
    {
      int ch = tid;
      int row = ch >> 2, col8 = (ch & 3) * 8;
      gload16(Ab + (m0 + row) * 1024 + kt * 32 + col8, &As[buf][ch * 8]);
    }
#pragma unroll
    for (int i = 0; i < 2; ++i) {
      int ch = tid + i * 256;
      int row = ch >> 2, col8 = (ch & 3) * 8;
      gload16(Bw + (n0 + row) * 1024 + kt * 32 + col8, &Bs[buf][ch * 8]);
    }
  };

  stage(0, 0);
  __syncthreads();

  for (int kt = 0; kt < 32; ++kt) {
    const int cur = kt & 1;
    if (kt < 31) stage(cur ^ 1, kt + 1);
    bf16x8 af[2], bfr[4];
#pragma unroll
    for (int mi = 0; mi < 2; ++mi)
      af[mi] = *(const bf16x8*)&As[cur][(wm * 32 + mi * 16 + c) * 32 + g * 8];
#pragma unroll
    for (int ni = 0; ni < 4; ++ni)
      bfr[ni] = *(const bf16x8*)&Bs[cur][(wn * 64 + ni * 16 + c) * 32 + g * 8];
#pragma unroll
    for (int mi = 0; mi < 2; ++mi)
#pragma unroll
      for (int ni = 0; ni < 4; ++ni)
        acc[mi][ni] = __builtin_amdgcn_mfma_f32_16x16x32_bf16(
            af[mi], bfr[ni], acc[mi][ni], 0, 0, 0);
    __syncthreads();
  }

  const int gm = m0 + wm * 32;
  const int gn = n0 + wn * 64;
#pragma unroll
  for (int mi = 0; mi < 2; ++mi)
#pragma unroll
    for (int ni = 0; ni < 4; ++ni)
#pragma unroll
      for (int r = 0; r < 4; ++r) {
        int m = gm + mi * 16 + 4 * g + r;
        int n = gn + ni * 16 + c;
        Out[m * 1024 + n] = acc[mi][ni][r] + bias[n];
      }
}

// ---------------------------------------------------------------------------
// Workspace layout (bytes):
//   0        xb   [4096,1024] bf16   8388608
//   8388608  Wqb  [1024,1024] bf16   2097152
//  10485760  Wkb                     2097152
//  12582912  Wvb                     2097152
//  14680064  Wob                     2097152
//  16777216  Qb   [B,H,T,D]  bf16    8388608   (pre-scaled by 0.125*log2e)
//  25165824  Kb   [B,H,T,D]  bf16    8388608
//  33554432  Vt   [B,H,D,T] bf16 pi-permuted   8388608
//  41943040  Ob   [4096,1024] bf16   8388608
// ---------------------------------------------------------------------------
extern "C" void kernel_launch(void* const* d_in, const int* in_sizes, int n_in,
                              void* d_out, int out_size, void* d_ws, size_t ws_size,
                              hipStream_t stream) {
  const float* x  = (const float*)d_in[0];
  const float* Wq = (const float*)d_in[1];
  const float* Wk = (const float*)d_in[2];
  const float* Wv = (const float*)d_in[3];
  const float* Wo = (const float*)d_in[4];
  const float* bo = (const float*)d_in[5];
  char* ws = (char*)d_ws;
  u16* xb  = (u16*)(ws);
  u16* wqb = (u16*)(ws + 8388608);
  u16* wkb = (u16*)(ws + 10485760);
  u16* wvb = (u16*)(ws + 12582912);
  u16* wob = (u16*)(ws + 14680064);
  u16* Qb  = (u16*)(ws + 16777216);
  u16* Kb  = (u16*)(ws + 25165824);
  u16* Vt  = (u16*)(ws + 33554432);
  u16* Ob  = (u16*)(ws + 41943040);

  convert_all<<<8192, 256, 0, stream>>>(x, Wq, Wk, Wv, Wo,
                                        xb, wqb, wkb, wvb, wob);
  gemm_qkv<<<dim3(768), 256, 0, stream>>>(xb, wqb, wkb, wvb, Qb, Kb, Vt);
  attn<<<dim3(1024), 256, 0, stream>>>(Qb, Kb, Vt, Ob);
  gemm_out<<<dim3(512), 256, 0, stream>>>(Ob, wob, bo, (float*)d_out);
}